// Round 22
// baseline (150.347 us; speedup 1.0000x reference)
//
#include <hip/hip_runtime.h>

// Problem constants
#define B_   16
#define C_   512
#define N_   1024   // H*W
#define L_   512
#define CTX_ 768
#define NH_  8
#define HD_  64
#define EPS_ 1e-5f

typedef short bfrag  __attribute__((ext_vector_type(8)));  // 8 x bf16 bits
typedef short bfrag4 __attribute__((ext_vector_type(4)));  // 4 x bf16 bits
typedef float f32x4  __attribute__((ext_vector_type(4)));

// manual RNE f32->bf16 (finite inputs); measured equal to native (r10).
__device__ __forceinline__ ushort f2bf(float f) {
  union { float f; unsigned u; } v; v.f = f;
  unsigned r = v.u + 0x7fffu + ((v.u >> 16) & 1u);
  return (ushort)(r >> 16);
}

__device__ __forceinline__ f32x4 mfma16(bfrag a, bfrag b, f32x4 c) {
  return __builtin_amdgcn_mfma_f32_16x16x32_bf16(a, b, c, 0, 0, 0);
}
__device__ __forceinline__ f32x4 mfma16k16(bfrag4 a, bfrag4 b, f32x4 c) {
  return __builtin_amdgcn_mfma_f32_16x16x16bf16_1k(a, b, c, 0, 0, 0);
}
// pack 2 f32 -> 1 dword of 2 bf16 (lo in [15:0], hi in [31:16]), RNE
__device__ __forceinline__ unsigned cvt_pk_bf16(float lo, float hi) {
  unsigned d;
  asm("v_cvt_pk_bf16_f32 %0, %1, %2" : "=v"(d) : "v"(lo), "v"(hi));
  return d;
}

// async global->LDS, 16B/lane. dst must be wave-uniform base + lane*16.
__device__ __forceinline__ void g2l16(const ushort* g, ushort* l) {
  __builtin_amdgcn_global_load_lds(
      (const __attribute__((address_space(1))) void*)g,
      (__attribute__((address_space(3))) void*)l, 16, 0, 0);
}

// ---------------------------------------------------------------------------
// fused casts: context (1572864 f4) + Wctx (98304) + Wq/Wk/Wv/Wo (65536 each).
// ---------------------------------------------------------------------------
__global__ __launch_bounds__(256) void cast6_kernel(
    const float* __restrict__ s0, const float* __restrict__ s1,
    const float* __restrict__ s2, const float* __restrict__ s3,
    const float* __restrict__ s4, const float* __restrict__ s5,
    ushort* __restrict__ d0, ushort* __restrict__ d1, ushort* __restrict__ d2,
    ushort* __restrict__ d3, ushort* __restrict__ d4, ushort* __restrict__ d5) {
  int i = blockIdx.x * 256 + threadIdx.x;   // float4 index, total 1933312
  const float* src; ushort* dst; int off;
  if      (i < 1572864) { src = s0; dst = d0; off = i; }            // context
  else if (i < 1671168) { src = s1; dst = d1; off = i - 1572864; }  // Wctx
  else if (i < 1736704) { src = s2; dst = d2; off = i - 1671168; }  // Wq
  else if (i < 1802240) { src = s3; dst = d3; off = i - 1736704; }  // Wk
  else if (i < 1867776) { src = s4; dst = d4; off = i - 1802240; }  // Wv
  else                  { src = s5; dst = d5; off = i - 1867776; }  // Wo
  float4 vv = ((const float4*)src)[off];
  ushort4 o;
  o.x = f2bf(vv.x); o.y = f2bf(vv.y); o.z = f2bf(vv.z); o.w = f2bf(vv.w);
  ((ushort4*)dst)[off] = o;
}

// ---------------------------------------------------------------------------
// LayerNorm over C with transpose (B,C,N) -> bf16 hn[(b*N+n)*C + c].
// ---------------------------------------------------------------------------
__global__ __launch_bounds__(1024) void ln_kernel(const float* __restrict__ x,
                                                  const float* __restrict__ w,
                                                  const float* __restrict__ bia,
                                                  ushort* __restrict__ hn) {
  const int b  = blockIdx.x;
  const int n0 = blockIdx.y * 64;
  const int tid = threadIdx.x;
  const int nx = tid & 63, cg = tid >> 6;   // cg 0..15
  const float* xb = x + (size_t)b * C_ * N_;

  float s = 0.f, s2 = 0.f;
  for (int c = cg; c < C_; c += 16) {
    float v = xb[(size_t)c * N_ + n0 + nx];
    s += v; s2 += v * v;
  }
  __shared__ float red[2][16][64];
  __shared__ float mean[64], rstd[64];
  red[0][cg][nx] = s; red[1][cg][nx] = s2;
  __syncthreads();
  if (cg == 0) {
    float ss = 0.f, ss2 = 0.f;
#pragma unroll
    for (int i = 0; i < 16; ++i) { ss += red[0][i][nx]; ss2 += red[1][i][nx]; }
    float mu  = ss * (1.f / C_);
    float var = ss2 * (1.f / C_) - mu * mu;
    mean[nx] = mu;
    rstd[nx] = rsqrtf(var + EPS_);
  }
  __syncthreads();

  __shared__ float tile[64][65];
  for (int ct = 0; ct < 8; ++ct) {
    const int c0 = ct * 64;
    for (int cy = cg; cy < 64; cy += 16)
      tile[cy][nx] = xb[(size_t)(c0 + cy) * N_ + n0 + nx];
    __syncthreads();
    const int cx = tid & 63, ng = tid >> 6;
    const float wv = w[c0 + cx], bv = bia[c0 + cx];
    for (int ny = ng; ny < 64; ny += 16) {
      float val = (tile[cx][ny] - mean[ny]) * rstd[ny] * wv + bv;
      hn[((size_t)b * N_ + n0 + ny) * C_ + c0 + cx] = f2bf(val);
    }
    __syncthreads();
  }
}

// ---------------------------------------------------------------------------
// Shared GEMM core (bf16 inputs): 128x128x32 tile, 4 waves, 4x4 frags.
// global_load_lds width-16 staging into LINEAR [128][32] LDS, XOR-swizzled
// source/read quad (both-sides involution).
// ---------------------------------------------------------------------------
__device__ __forceinline__ void gemm_core(const ushort* __restrict__ A,
                                          const ushort* __restrict__ W,
                                          int K, ushort* la, ushort* lb,
                                          f32x4 acc[4][4],
                                          int tid, int wm, int we, int col, int rg) {
  const int lane = tid & 63, w = tid >> 6;
  const int rloc = lane >> 2, pt = lane & 3;
  const int pts = pt ^ ((rloc >> 1) & 3);       // source quad pre-swizzle
  const int qsel = (rg ^ ((col >> 1) & 3)) * 8; // read quad select (ushorts)

  for (int k0 = 0; k0 < K; k0 += 32) {
#pragma unroll
    for (int c = 0; c < 2; ++c) {
      const int chunk = w + c * 4;              // 16-row chunk, wave-uniform
      const int row = chunk * 16 + rloc;
      g2l16(A + (size_t)row * K + k0 + pts * 8, la + chunk * 512);
      g2l16(W + (size_t)row * K + k0 + pts * 8, lb + chunk * 512);
    }
    __syncthreads();
    bfrag af[4], bf[4];
#pragma unroll
    for (int i = 0; i < 4; ++i) {
      af[i] = *(const bfrag*)&la[(wm + i * 16 + col) * 32 + qsel];
      bf[i] = *(const bfrag*)&lb[(we + i * 16 + col) * 32 + qsel];
    }
#pragma unroll
    for (int i = 0; i < 4; ++i)
#pragma unroll
      for (int j = 0; j < 4; ++j)
        acc[i][j] = mfma16(af[i], bf[j], acc[i][j]);
    __syncthreads();
  }
}

// ---------------------------------------------------------------------------
// ctx projection alone (256 blocks): ctx = ctxb @ Wctx^T (K=768).
// Short serial prefix: only this blocks gemm_kvq (kv needs ctx).
// XCD-friendly map: same-m blocks 64 apart.
// ---------------------------------------------------------------------------
__global__ __launch_bounds__(256) void gemm_ctx(const ushort* __restrict__ ctxb,
                                                const ushort* __restrict__ Wctxb,
                                                ushort* __restrict__ ctxo) {
  __shared__ ushort la[128 * 32];
  __shared__ ushort lb[128 * 32];
  const int bid = blockIdx.x;
  const int tid = threadIdx.x, lane = tid & 63, w = tid >> 6;
  const int wm = (w >> 1) * 64, we = (w & 1) * 64;
  const int col = lane & 15, rg = lane >> 4;
  const int m0 = (bid & 63) * 128, e0 = (bid >> 6) * 128;

  f32x4 acc[4][4] = {};
  gemm_core(ctxb + (size_t)m0 * CTX_, Wctxb + (size_t)e0 * CTX_, CTX_,
            la, lb, acc, tid, wm, we, col, rg);

#pragma unroll
  for (int i = 0; i < 4; ++i)
#pragma unroll
    for (int j = 0; j < 4; ++j)
#pragma unroll
      for (int r = 0; r < 4; ++r)
        ctxo[(size_t)(m0 + wm + i * 16 + rg * 4 + r) * 512 + e0 + we + j * 16 + col] =
            f2bf(acc[i][j][r]);
}

// ---------------------------------------------------------------------------
// Round-22: FUSED K + V + Q projections (1024 blocks = 4/CU). All three
// depend only on {ctx, hn}, both ready -> co-dispatch overlaps them (stream
// is serial; fusion is the only overlap mechanism). kv path byte-identical
// to r21 gemm_kv; q path to r21 ctxq's q half.
// bid 0..511: kv (m=bid&63, y=bid>>6: y>>2=isv, y&3=e). 512..1023: q.
// ---------------------------------------------------------------------------
__global__ __launch_bounds__(256) void gemm_kvq(const ushort* __restrict__ A,
                                                const ushort* __restrict__ Wk,
                                                const ushort* __restrict__ Wv,
                                                ushort* __restrict__ Ko,
                                                ushort* __restrict__ Vt_g,
                                                const ushort* __restrict__ hn,
                                                const ushort* __restrict__ Wqb,
                                                ushort* __restrict__ qo) {
  __shared__ ushort la[128 * 32];
  __shared__ ushort lb[128 * 32];
  __shared__ float T[16][132];
  const int bid = blockIdx.x;
  const int tid = threadIdx.x, lane = tid & 63, w = tid >> 6;
  const int wm = (w >> 1) * 64, we = (w & 1) * 64;
  const int col = lane & 15, rg = lane >> 4;

  if (bid < 512) {
    // ---- K / V projection ----
    const int y = bid >> 6;                 // 0..7
    const int isv = y >> 2;
    const ushort* W = isv ? Wv : Wk;
    const int m0 = (bid & 63) * 128, e0 = (y & 3) * 128;

    f32x4 acc[4][4] = {};
    gemm_core(A + (size_t)m0 * C_, W + (size_t)e0 * C_, C_, la, lb, acc,
              tid, wm, we, col, rg);

    if (!isv) {
#pragma unroll
      for (int i = 0; i < 4; ++i)
#pragma unroll
        for (int j = 0; j < 4; ++j)
#pragma unroll
          for (int r = 0; r < 4; ++r)
            Ko[(size_t)(m0 + wm + i * 16 + rg * 4 + r) * 512 + e0 + we + j * 16 + col] =
                f2bf(acc[i][j][r]);
    } else {
      // transposed V write via LDS tile: e-major output
      const int b = m0 >> 9, l0 = m0 & 511;
#pragma unroll
      for (int g = 0; g < 8; ++g) {
        if ((w & 1) == (g >> 2)) {        // wave-uniform: we-half owns this group
          const int j = g & 3;
#pragma unroll
          for (int i = 0; i < 4; ++i)
            *(f32x4*)&T[col][wm + i * 16 + rg * 4] = acc[i][j];
        }
        __syncthreads();
        const int n = tid & 127;
        for (int cc = tid >> 7; cc < 16; cc += 2) {
          const int e = e0 + g * 16 + cc;
          Vt_g[((size_t)b * 512 + e) * 512 + l0 + n] = f2bf(T[cc][n]);
        }
        __syncthreads();
      }
    }
  } else {
    // ---- Q projection ----
    const int b2 = bid - 512;
    const int m0 = (b2 & 127) * 128, e0 = (b2 >> 7) * 128;

    f32x4 acc[4][4] = {};
    gemm_core(hn + (size_t)m0 * C_, Wqb + (size_t)e0 * C_, C_, la, lb, acc,
              tid, wm, we, col, rg);

#pragma unroll
    for (int i = 0; i < 4; ++i)
#pragma unroll
      for (int j = 0; j < 4; ++j)
#pragma unroll
        for (int r = 0; r < 4; ++r)
          qo[(size_t)(m0 + wm + i * 16 + rg * 4 + r) * 512 + e0 + we + j * 16 + col] =
              f2bf(acc[i][j][r]);
  }
}

// o-projection + transposed residual epilogue: out[b][c][n] = (A@Wo^T)+x
__global__ __launch_bounds__(256) void gemm_res(const ushort* __restrict__ A,
                                                const ushort* __restrict__ W,
                                                const float* __restrict__ x,
                                                float* __restrict__ out) {
  __shared__ ushort la[128 * 32];
  __shared__ ushort lb[128 * 32];
  __shared__ float T[16][132];
  const int m0 = blockIdx.x * 128, e0 = blockIdx.y * 128;
  const int tid = threadIdx.x, lane = tid & 63, w = tid >> 6;
  const int wm = (w >> 1) * 64, we = (w & 1) * 64;
  const int col = lane & 15, rg = lane >> 4;

  f32x4 acc[4][4] = {};
  gemm_core(A + (size_t)m0 * C_, W + (size_t)e0 * C_, C_, la, lb, acc, tid, wm, we, col, rg);

  const int b = m0 >> 10, n0l = m0 & 1023;
#pragma unroll
  for (int g = 0; g < 8; ++g) {
    if ((w & 1) == (g >> 2)) {          // wave-uniform: we-half owns this group
      const int j = g & 3;
#pragma unroll
      for (int i = 0; i < 4; ++i)
        *(f32x4*)&T[col][wm + i * 16 + rg * 4] = acc[i][j];
    }
    __syncthreads();
    const int n = tid & 127;
    for (int cc = tid >> 7; cc < 16; cc += 2) {
      const int c = e0 + g * 16 + cc;
      const size_t idx = (size_t)b * C_ * N_ + (size_t)c * N_ + n0l + n;
      out[idx] = T[cc][n] + x[idx];
    }
    __syncthreads();
  }
}

// ---------------------------------------------------------------------------
// MFMA flash cross-attention (swapped QK^T, P in registers, double-buffered,
// XCD-swizzled, V pre-transposed). Unchanged from r18.
// ---------------------------------------------------------------------------
__global__ __launch_bounds__(256) void attn_mfma(const ushort* __restrict__ q,
                                                 const ushort* __restrict__ k,
                                                 const ushort* __restrict__ vt,
                                                 const int* __restrict__ mask,
                                                 ushort* __restrict__ o) {
  __shared__ ushort Kl[2][64 * 72];   // [buf][key][72]
  __shared__ ushort Vt[2][64 * 72];   // [buf][d][72]
  __shared__ float mlb[2][64];

  const int lin = blockIdx.x;           // 0..1023
  const int hb = lin & 127, qb = lin >> 7;
  const int h = hb & 7, b = hb >> 3;
  const int q0 = qb * 128;
  const int tid = threadIdx.x, lane = tid & 63, w = tid >> 6;
  const int col = lane & 15, rg = lane >> 4;
  const int wq = w * 32;
  const float C1 = 0.18033688011112042f;  // 0.125 * log2(e)

  bfrag qf[2][2];
#pragma unroll
  for (int mi = 0; mi < 2; ++mi)
#pragma unroll
    for (int kc = 0; kc < 2; ++kc)
      qf[mi][kc] = *(const bfrag*)
          &q[((size_t)b * N_ + q0 + wq + mi * 16 + col) * C_ + h * HD_ + kc * 32 + rg * 8];

  f32x4 oa[2][4] = {};
  float l_part[2] = {0.f, 0.f};   // per-lane denominator for q = col

  // prologue: stage tile 0 into buf 0
  {
#pragma unroll
    for (int it = 0; it < 2; ++it) {
      const int idx = it * 256 + tid;
      const int key = idx >> 3, part = idx & 7;
      *(int4*)&Kl[0][key * 72 + part * 8] =
          *(const int4*)&k[((size_t)b * L_ + key) * C_ + h * HD_ + part * 8];
    }
#pragma unroll
    for (int it = 0; it < 2; ++it) {    // V^T: row d, 8 keys per b128
      const int idx = it * 256 + tid;
      const int d = idx >> 3, k8 = (idx & 7) * 8;
      *(int4*)&Vt[0][d * 72 + k8] =
          *(const int4*)&vt[((size_t)b * 512 + h * HD_ + d) * 512 + k8];
    }
    if (tid < 64) mlb[0][tid] = mask[b * L_ + tid] ? 0.f : -1e30f;
  }
  __syncthreads();

  for (int t = 0; t < 8; ++t) {
    const int cur = t & 1;
    // issue next-tile loads into registers (retire at the write phase)
    int4 kreg[2];
    int4 vreg[2];
    float mreg = 0.f;
    if (t < 7) {
      const int l0n = (t + 1) * 64;
#pragma unroll
      for (int it = 0; it < 2; ++it) {
        const int idx = it * 256 + tid;
        const int key = idx >> 3, part = idx & 7;
        kreg[it] = *(const int4*)&k[((size_t)b * L_ + l0n + key) * C_ + h * HD_ + part * 8];
      }
#pragma unroll
      for (int it = 0; it < 2; ++it) {
        const int idx = it * 256 + tid;
        const int d = idx >> 3, k8 = (idx & 7) * 8;
        vreg[it] = *(const int4*)&vt[((size_t)b * 512 + h * HD_ + d) * 512 + l0n + k8];
      }
      if (tid < 64) mreg = mask[b * L_ + l0n + tid] ? 0.f : -1e30f;
    }

    // ---- compute on buf cur ----
    const ushort* Kc = &Kl[cur][0];
    const ushort* Vc = &Vt[cur][0];
    f32x4 s2[2][4] = {};
#pragma unroll
    for (int kc = 0; kc < 2; ++kc) {
      bfrag kf[4];
#pragma unroll
      for (int ni = 0; ni < 4; ++ni)
        kf[ni] = *(const bfrag*)&Kc[(ni * 16 + col) * 72 + kc * 32 + rg * 8];
#pragma unroll
      for (int mi = 0; mi < 2; ++mi)
#pragma unroll
        for (int ni = 0; ni < 4; ++ni)
          s2[mi][ni] = mfma16(kf[ni], qf[mi][kc], s2[mi][ni]);
    }
    bfrag4 pf[2][4];
#pragma unroll
    for (int ni = 0; ni < 4; ++ni) {
      const f32x4 bias4 = *(const f32x4*)&mlb[cur][ni * 16 + rg * 4];
#pragma unroll
      for (int mi = 0; mi < 2; ++mi) {
        const float p0 = exp2f(fmaf(s2[mi][ni][0], C1, bias4[0]));
        const float p1 = exp2f(fmaf(s2[mi][ni][1], C1, bias4[1]));
        const float p2 = exp2f(fmaf(s2[mi][ni][2], C1, bias4[2]));
        const float p3 = exp2f(fmaf(s2[mi][ni][3], C1, bias4[3]));
        l_part[mi] += (p0 + p1) + (p2 + p3);
        union { bfrag4 v; unsigned u[2]; } pk;
        pk.u[0] = cvt_pk_bf16(p0, p1);
        pk.u[1] = cvt_pk_bf16(p2, p3);
        pf[mi][ni] = pk.v;
      }
    }
#pragma unroll
    for (int ni = 0; ni < 4; ++ni) {
      bfrag4 vf[4];
#pragma unroll
      for (int di = 0; di < 4; ++di)
        vf[di] = *(const bfrag4*)&Vc[(di * 16 + col) * 72 + ni * 16 + rg * 4];
#pragma unroll
      for (int mi = 0; mi < 2; ++mi)
#pragma unroll
        for (int di = 0; di < 4; ++di)
          oa[mi][di] = mfma16k16(pf[mi][ni], vf[di], oa[mi][di]);
    }

    // ---- write next tile into the other buffer ----
    if (t < 7) {
      const int nb = cur ^ 1;
#pragma unroll
      for (int it = 0; it < 2; ++it) {
        const int idx = it * 256 + tid;
        const int key = idx >> 3, part = idx & 7;
        *(int4*)&Kl[nb][key * 72 + part * 8] = kreg[it];
      }
#pragma unroll
      for (int it = 0; it < 2; ++it) {
        const int idx = it * 256 + tid;
        const int d = idx >> 3, k8 = (idx & 7) * 8;
        *(int4*)&Vt[nb][d * 72 + k8] = vreg[it];
      }
      if (tid < 64) mlb[nb][tid] = mreg;
    }
    __syncthreads();   // one barrier per tile: readers done + next buf ready
  }

  // denominator: reduce across rg groups, bpermute 1/l to row layout
  float linv[2][4];
#pragma unroll
  for (int mi = 0; mi < 2; ++mi) {
    float l = l_part[mi];
    l += __shfl_xor(l, 16);
    l += __shfl_xor(l, 32);
#pragma unroll
    for (int r = 0; r < 4; ++r) {
      int lv = __builtin_amdgcn_ds_bpermute((rg * 4 + r) * 4, __float_as_int(l));
      linv[mi][r] = 1.f / __int_as_float(lv);
    }
  }
#pragma unroll
  for (int mi = 0; mi < 2; ++mi)
#pragma unroll
    for (int r = 0; r < 4; ++r) {
      const size_t row = (size_t)b * N_ + q0 + wq + mi * 16 + rg * 4 + r;
#pragma unroll
      for (int di = 0; di < 4; ++di)
        o[row * C_ + h * HD_ + di * 16 + col] = f2bf(oa[mi][di][r] * linv[mi][r]);
    }
}

// ---------------------------------------------------------------------------
// Launch
// ---------------------------------------------------------------------------
extern "C" void kernel_launch(void* const* d_in, const int* in_sizes, int n_in,
                              void* d_out, int out_size, void* d_ws, size_t ws_size,
                              hipStream_t stream) {
  (void)in_sizes; (void)n_in; (void)out_size; (void)ws_size;
  const float* x       = (const float*)d_in[0];
  const float* context = (const float*)d_in[1];
  const int*   mask    = (const int*)d_in[2];
  const float* ln_w    = (const float*)d_in[3];
  const float* ln_b    = (const float*)d_in[4];
  const float* Wq      = (const float*)d_in[5];
  const float* Wk      = (const float*)d_in[6];
  const float* Wv      = (const float*)d_in[7];
  const float* Wo      = (const float*)d_in[8];
  const float* Wctx    = (const float*)d_in[9];

  char* wsb = (char*)d_ws;
  ushort* qb    = (ushort*)(wsb + 0);          // 16384x512 bf16
  ushort* kb    = (ushort*)(wsb + 16777216);   //  8192x512
  ushort* vb    = (ushort*)(wsb + 25165824);   //  8192x512 (V^T: (b*512+e)*512+l)
  ushort* atto  = (ushort*)(wsb + 33554432);   // 16384x512 (attn out)
  ushort* ctx   = (ushort*)(wsb + 50331648);   //  8192x512 (projected context)
  ushort* wctxb = (ushort*)(wsb + 58720256);   //   512x768
  ushort* wqb   = (ushort*)(wsb + 59506688);   //   512x512 each
  ushort* wkb   = (ushort*)(wsb + 60030976);
  ushort* wvb   = (ushort*)(wsb + 60555264);
  ushort* wob   = (ushort*)(wsb + 61079552);
  ushort* hn    = (ushort*)(wsb + 61603840);   // 16384x512 bf16 (LN'd hidden)
  ushort* ctxb  = (ushort*)(wsb + 78381056);   //  8192x768 bf16 (context cast)
  // total 90,963,968 bytes

  cast6_kernel<<<7552, 256, 0, stream>>>(context, Wctx, Wq, Wk, Wv, Wo,
                                         ctxb, wctxb, wqb, wkb, wvb, wob);
  ln_kernel<<<dim3(B_, N_ / 64), 1024, 0, stream>>>(x, ln_w, ln_b, hn);
  // short serial prefix: ctx = ctxb @ Wctx^T (only dependency of kv)
  gemm_ctx<<<256, 256, 0, stream>>>(ctxb, wctxb, ctx);
  // FUSED K + V + Q projections (1024 blocks = 4/CU)
  gemm_kvq<<<1024, 256, 0, stream>>>(ctx, wkb, wvb, kb, vb, hn, wqb, qb);
  // XCD-swizzled 1D grid (T1): all q-blocks of one (b,h) on the same XCD
  attn_mfma<<<1024, 256, 0, stream>>>(qb, kb, vb, mask, atto);
  // out = transpose(atto @ Wo^T) + x, fused epilogue
  gemm_res<<<dim3(128, 4), 256, 0, stream>>>(atto, wob, x, (float*)d_out);
}

// Round 23
// 146.523 us; speedup vs baseline: 1.0261x; 1.0261x over previous
//
#include <hip/hip_runtime.h>

// Problem constants
#define B_   16
#define C_   512
#define N_   1024   // H*W
#define L_   512
#define CTX_ 768
#define NH_  8
#define HD_  64
#define EPS_ 1e-5f

typedef short bfrag  __attribute__((ext_vector_type(8)));  // 8 x bf16 bits
typedef short bfrag4 __attribute__((ext_vector_type(4)));  // 4 x bf16 bits
typedef float f32x4  __attribute__((ext_vector_type(4)));

// manual RNE f32->bf16 (finite inputs); measured equal to native (r10).
__device__ __forceinline__ ushort f2bf(float f) {
  union { float f; unsigned u; } v; v.f = f;
  unsigned r = v.u + 0x7fffu + ((v.u >> 16) & 1u);
  return (ushort)(r >> 16);
}

__device__ __forceinline__ f32x4 mfma16(bfrag a, bfrag b, f32x4 c) {
  return __builtin_amdgcn_mfma_f32_16x16x32_bf16(a, b, c, 0, 0, 0);
}
__device__ __forceinline__ f32x4 mfma16k16(bfrag4 a, bfrag4 b, f32x4 c) {
  return __builtin_amdgcn_mfma_f32_16x16x16bf16_1k(a, b, c, 0, 0, 0);
}
// pack 2 f32 -> 1 dword of 2 bf16 (lo in [15:0], hi in [31:16]), RNE
__device__ __forceinline__ unsigned cvt_pk_bf16(float lo, float hi) {
  unsigned d;
  asm("v_cvt_pk_bf16_f32 %0, %1, %2" : "=v"(d) : "v"(lo), "v"(hi));
  return d;
}

// async global->LDS, 16B/lane. dst must be wave-uniform base + lane*16.
__device__ __forceinline__ void g2l16(const ushort* g, ushort* l) {
  __builtin_amdgcn_global_load_lds(
      (const __attribute__((address_space(1))) void*)g,
      (__attribute__((address_space(3))) void*)l, 16, 0, 0);
}

// ---------------------------------------------------------------------------
// fused casts: context (1572864 f4) + Wctx (98304) + Wq/Wk/Wv/Wo (65536 each).
// ---------------------------------------------------------------------------
__global__ __launch_bounds__(256) void cast6_kernel(
    const float* __restrict__ s0, const float* __restrict__ s1,
    const float* __restrict__ s2, const float* __restrict__ s3,
    const float* __restrict__ s4, const float* __restrict__ s5,
    ushort* __restrict__ d0, ushort* __restrict__ d1, ushort* __restrict__ d2,
    ushort* __restrict__ d3, ushort* __restrict__ d4, ushort* __restrict__ d5) {
  int i = blockIdx.x * 256 + threadIdx.x;   // float4 index, total 1933312
  const float* src; ushort* dst; int off;
  if      (i < 1572864) { src = s0; dst = d0; off = i; }            // context
  else if (i < 1671168) { src = s1; dst = d1; off = i - 1572864; }  // Wctx
  else if (i < 1736704) { src = s2; dst = d2; off = i - 1671168; }  // Wq
  else if (i < 1802240) { src = s3; dst = d3; off = i - 1736704; }  // Wk
  else if (i < 1867776) { src = s4; dst = d4; off = i - 1802240; }  // Wv
  else                  { src = s5; dst = d5; off = i - 1867776; }  // Wo
  float4 vv = ((const float4*)src)[off];
  ushort4 o;
  o.x = f2bf(vv.x); o.y = f2bf(vv.y); o.z = f2bf(vv.z); o.w = f2bf(vv.w);
  ((ushort4*)dst)[off] = o;
}

// ---------------------------------------------------------------------------
// LayerNorm over C with transpose (B,C,N) -> bf16 hn[(b*N+n)*C + c].
// ---------------------------------------------------------------------------
__global__ __launch_bounds__(1024) void ln_kernel(const float* __restrict__ x,
                                                  const float* __restrict__ w,
                                                  const float* __restrict__ bia,
                                                  ushort* __restrict__ hn) {
  const int b  = blockIdx.x;
  const int n0 = blockIdx.y * 64;
  const int tid = threadIdx.x;
  const int nx = tid & 63, cg = tid >> 6;   // cg 0..15
  const float* xb = x + (size_t)b * C_ * N_;

  float s = 0.f, s2 = 0.f;
  for (int c = cg; c < C_; c += 16) {
    float v = xb[(size_t)c * N_ + n0 + nx];
    s += v; s2 += v * v;
  }
  __shared__ float red[2][16][64];
  __shared__ float mean[64], rstd[64];
  red[0][cg][nx] = s; red[1][cg][nx] = s2;
  __syncthreads();
  if (cg == 0) {
    float ss = 0.f, ss2 = 0.f;
#pragma unroll
    for (int i = 0; i < 16; ++i) { ss += red[0][i][nx]; ss2 += red[1][i][nx]; }
    float mu  = ss * (1.f / C_);
    float var = ss2 * (1.f / C_) - mu * mu;
    mean[nx] = mu;
    rstd[nx] = rsqrtf(var + EPS_);
  }
  __syncthreads();

  __shared__ float tile[64][65];
  for (int ct = 0; ct < 8; ++ct) {
    const int c0 = ct * 64;
    for (int cy = cg; cy < 64; cy += 16)
      tile[cy][nx] = xb[(size_t)(c0 + cy) * N_ + n0 + nx];
    __syncthreads();
    const int cx = tid & 63, ng = tid >> 6;
    const float wv = w[c0 + cx], bv = bia[c0 + cx];
    for (int ny = ng; ny < 64; ny += 16) {
      float val = (tile[cx][ny] - mean[ny]) * rstd[ny] * wv + bv;
      hn[((size_t)b * N_ + n0 + ny) * C_ + c0 + cx] = f2bf(val);
    }
    __syncthreads();
  }
}

// ---------------------------------------------------------------------------
// Shared GEMM core (bf16 inputs): 128x128x32 tile, 4 waves, 4x4 frags.
// global_load_lds width-16 staging into LINEAR [128][32] LDS, XOR-swizzled
// source/read quad (both-sides involution).
// ---------------------------------------------------------------------------
__device__ __forceinline__ void gemm_core(const ushort* __restrict__ A,
                                          const ushort* __restrict__ W,
                                          int K, ushort* la, ushort* lb,
                                          f32x4 acc[4][4],
                                          int tid, int wm, int we, int col, int rg) {
  const int lane = tid & 63, w = tid >> 6;
  const int rloc = lane >> 2, pt = lane & 3;
  const int pts = pt ^ ((rloc >> 1) & 3);       // source quad pre-swizzle
  const int qsel = (rg ^ ((col >> 1) & 3)) * 8; // read quad select (ushorts)

  for (int k0 = 0; k0 < K; k0 += 32) {
#pragma unroll
    for (int c = 0; c < 2; ++c) {
      const int chunk = w + c * 4;              // 16-row chunk, wave-uniform
      const int row = chunk * 16 + rloc;
      g2l16(A + (size_t)row * K + k0 + pts * 8, la + chunk * 512);
      g2l16(W + (size_t)row * K + k0 + pts * 8, lb + chunk * 512);
    }
    __syncthreads();
    bfrag af[4], bf[4];
#pragma unroll
    for (int i = 0; i < 4; ++i) {
      af[i] = *(const bfrag*)&la[(wm + i * 16 + col) * 32 + qsel];
      bf[i] = *(const bfrag*)&lb[(we + i * 16 + col) * 32 + qsel];
    }
#pragma unroll
    for (int i = 0; i < 4; ++i)
#pragma unroll
      for (int j = 0; j < 4; ++j)
        acc[i][j] = mfma16(af[i], bf[j], acc[i][j]);
    __syncthreads();
  }
}

// ---------------------------------------------------------------------------
// FUSED ctx + q projections (r21-proven; r22's ctx-prefix split regressed).
// Blocks 0..255: ctx = ctxb @ Wctx^T (K=768), same-m blocks 64 apart.
// Blocks 256..767: q = hn @ Wq^T (K=512), same-m blocks 128 apart.
// ---------------------------------------------------------------------------
__global__ __launch_bounds__(256) void gemm_ctxq(const ushort* __restrict__ ctxb,
                                                 const ushort* __restrict__ Wctxb,
                                                 ushort* __restrict__ ctxo,
                                                 const ushort* __restrict__ hn,
                                                 const ushort* __restrict__ Wqb,
                                                 ushort* __restrict__ qo) {
  __shared__ ushort la[128 * 32];
  __shared__ ushort lb[128 * 32];
  const int bid = blockIdx.x;
  const int tid = threadIdx.x, lane = tid & 63, w = tid >> 6;
  const int wm = (w >> 1) * 64, we = (w & 1) * 64;
  const int col = lane & 15, rg = lane >> 4;

  const ushort* A; const ushort* W; ushort* out; int K, m0, e0;
  if (bid < 256) {
    m0 = (bid & 63) * 128; e0 = (bid >> 6) * 128;   // same-m blocks 64 apart
    A = ctxb; W = Wctxb; out = ctxo; K = CTX_;
  } else {
    const int b2 = bid - 256;
    m0 = (b2 & 127) * 128; e0 = (b2 >> 7) * 128;    // same-m blocks 128 apart
    A = hn; W = Wqb; out = qo; K = C_;
  }

  f32x4 acc[4][4] = {};
  gemm_core(A + (size_t)m0 * K, W + (size_t)e0 * K, K, la, lb, acc, tid, wm, we, col, rg);

#pragma unroll
  for (int i = 0; i < 4; ++i)
#pragma unroll
    for (int j = 0; j < 4; ++j)
#pragma unroll
      for (int r = 0; r < 4; ++r)
        out[(size_t)(m0 + wm + i * 16 + rg * 4 + r) * 512 + e0 + we + j * 16 + col] =
            f2bf(acc[i][j][r]);
}

// ---------------------------------------------------------------------------
// fused K+V projection: blockIdx.y<4 -> K-proj (row-major out), else V-proj
// with TRANSPOSED output vt[(b*512+e)*512+l].
// ---------------------------------------------------------------------------
__global__ __launch_bounds__(256) void gemm_kv(const ushort* __restrict__ A,
                                               const ushort* __restrict__ Wk,
                                               const ushort* __restrict__ Wv,
                                               ushort* __restrict__ Ko,
                                               ushort* __restrict__ Vt_g) {
  __shared__ ushort la[128 * 32];
  __shared__ ushort lb[128 * 32];
  __shared__ float T[16][132];
  const int isv = blockIdx.y >> 2;
  const ushort* W = isv ? Wv : Wk;
  const int m0 = blockIdx.x * 128, e0 = (blockIdx.y & 3) * 128;
  const int tid = threadIdx.x, lane = tid & 63, w = tid >> 6;
  const int wm = (w >> 1) * 64, we = (w & 1) * 64;
  const int col = lane & 15, rg = lane >> 4;

  f32x4 acc[4][4] = {};
  gemm_core(A + (size_t)m0 * C_, W + (size_t)e0 * C_, C_, la, lb, acc, tid, wm, we, col, rg);

  if (!isv) {
#pragma unroll
    for (int i = 0; i < 4; ++i)
#pragma unroll
      for (int j = 0; j < 4; ++j)
#pragma unroll
        for (int r = 0; r < 4; ++r)
          Ko[(size_t)(m0 + wm + i * 16 + rg * 4 + r) * 512 + e0 + we + j * 16 + col] =
              f2bf(acc[i][j][r]);
  } else {
    // transposed V write via LDS tile: e-major output
    const int b = m0 >> 9, l0 = m0 & 511;
#pragma unroll
    for (int g = 0; g < 8; ++g) {
      if ((w & 1) == (g >> 2)) {        // wave-uniform: we-half owns this group
        const int j = g & 3;
#pragma unroll
        for (int i = 0; i < 4; ++i)
          *(f32x4*)&T[col][wm + i * 16 + rg * 4] = acc[i][j];
      }
      __syncthreads();
      const int n = tid & 127;
      for (int cc = tid >> 7; cc < 16; cc += 2) {
        const int e = e0 + g * 16 + cc;
        Vt_g[((size_t)b * 512 + e) * 512 + l0 + n] = f2bf(T[cc][n]);
      }
      __syncthreads();
    }
  }
}

// o-projection + transposed residual epilogue: out[b][c][n] = (A@Wo^T)+x
__global__ __launch_bounds__(256) void gemm_res(const ushort* __restrict__ A,
                                                const ushort* __restrict__ W,
                                                const float* __restrict__ x,
                                                float* __restrict__ out) {
  __shared__ ushort la[128 * 32];
  __shared__ ushort lb[128 * 32];
  __shared__ float T[16][132];
  const int m0 = blockIdx.x * 128, e0 = blockIdx.y * 128;
  const int tid = threadIdx.x, lane = tid & 63, w = tid >> 6;
  const int wm = (w >> 1) * 64, we = (w & 1) * 64;
  const int col = lane & 15, rg = lane >> 4;

  f32x4 acc[4][4] = {};
  gemm_core(A + (size_t)m0 * C_, W + (size_t)e0 * C_, C_, la, lb, acc, tid, wm, we, col, rg);

  const int b = m0 >> 10, n0l = m0 & 1023;
#pragma unroll
  for (int g = 0; g < 8; ++g) {
    if ((w & 1) == (g >> 2)) {          // wave-uniform: we-half owns this group
      const int j = g & 3;
#pragma unroll
      for (int i = 0; i < 4; ++i)
        *(f32x4*)&T[col][wm + i * 16 + rg * 4] = acc[i][j];
    }
    __syncthreads();
    const int n = tid & 127;
    for (int cc = tid >> 7; cc < 16; cc += 2) {
      const int c = e0 + g * 16 + cc;
      const size_t idx = (size_t)b * C_ * N_ + (size_t)c * N_ + n0l + n;
      out[idx] = T[cc][n] + x[idx];
    }
    __syncthreads();
  }
}

// ---------------------------------------------------------------------------
// MFMA flash cross-attention (swapped QK^T, P in registers, double-buffered,
// XCD-swizzled, V pre-transposed). Unchanged from r18.
// ---------------------------------------------------------------------------
__global__ __launch_bounds__(256) void attn_mfma(const ushort* __restrict__ q,
                                                 const ushort* __restrict__ k,
                                                 const ushort* __restrict__ vt,
                                                 const int* __restrict__ mask,
                                                 ushort* __restrict__ o) {
  __shared__ ushort Kl[2][64 * 72];   // [buf][key][72]
  __shared__ ushort Vt[2][64 * 72];   // [buf][d][72]
  __shared__ float mlb[2][64];

  const int lin = blockIdx.x;           // 0..1023
  const int hb = lin & 127, qb = lin >> 7;
  const int h = hb & 7, b = hb >> 3;
  const int q0 = qb * 128;
  const int tid = threadIdx.x, lane = tid & 63, w = tid >> 6;
  const int col = lane & 15, rg = lane >> 4;
  const int wq = w * 32;
  const float C1 = 0.18033688011112042f;  // 0.125 * log2(e)

  bfrag qf[2][2];
#pragma unroll
  for (int mi = 0; mi < 2; ++mi)
#pragma unroll
    for (int kc = 0; kc < 2; ++kc)
      qf[mi][kc] = *(const bfrag*)
          &q[((size_t)b * N_ + q0 + wq + mi * 16 + col) * C_ + h * HD_ + kc * 32 + rg * 8];

  f32x4 oa[2][4] = {};
  float l_part[2] = {0.f, 0.f};   // per-lane denominator for q = col

  // prologue: stage tile 0 into buf 0
  {
#pragma unroll
    for (int it = 0; it < 2; ++it) {
      const int idx = it * 256 + tid;
      const int key = idx >> 3, part = idx & 7;
      *(int4*)&Kl[0][key * 72 + part * 8] =
          *(const int4*)&k[((size_t)b * L_ + key) * C_ + h * HD_ + part * 8];
    }
#pragma unroll
    for (int it = 0; it < 2; ++it) {    // V^T: row d, 8 keys per b128
      const int idx = it * 256 + tid;
      const int d = idx >> 3, k8 = (idx & 7) * 8;
      *(int4*)&Vt[0][d * 72 + k8] =
          *(const int4*)&vt[((size_t)b * 512 + h * HD_ + d) * 512 + k8];
    }
    if (tid < 64) mlb[0][tid] = mask[b * L_ + tid] ? 0.f : -1e30f;
  }
  __syncthreads();

  for (int t = 0; t < 8; ++t) {
    const int cur = t & 1;
    // issue next-tile loads into registers (retire at the write phase)
    int4 kreg[2];
    int4 vreg[2];
    float mreg = 0.f;
    if (t < 7) {
      const int l0n = (t + 1) * 64;
#pragma unroll
      for (int it = 0; it < 2; ++it) {
        const int idx = it * 256 + tid;
        const int key = idx >> 3, part = idx & 7;
        kreg[it] = *(const int4*)&k[((size_t)b * L_ + l0n + key) * C_ + h * HD_ + part * 8];
      }
#pragma unroll
      for (int it = 0; it < 2; ++it) {
        const int idx = it * 256 + tid;
        const int d = idx >> 3, k8 = (idx & 7) * 8;
        vreg[it] = *(const int4*)&vt[((size_t)b * 512 + h * HD_ + d) * 512 + l0n + k8];
      }
      if (tid < 64) mreg = mask[b * L_ + l0n + tid] ? 0.f : -1e30f;
    }

    // ---- compute on buf cur ----
    const ushort* Kc = &Kl[cur][0];
    const ushort* Vc = &Vt[cur][0];
    f32x4 s2[2][4] = {};
#pragma unroll
    for (int kc = 0; kc < 2; ++kc) {
      bfrag kf[4];
#pragma unroll
      for (int ni = 0; ni < 4; ++ni)
        kf[ni] = *(const bfrag*)&Kc[(ni * 16 + col) * 72 + kc * 32 + rg * 8];
#pragma unroll
      for (int mi = 0; mi < 2; ++mi)
#pragma unroll
        for (int ni = 0; ni < 4; ++ni)
          s2[mi][ni] = mfma16(kf[ni], qf[mi][kc], s2[mi][ni]);
    }
    bfrag4 pf[2][4];
#pragma unroll
    for (int ni = 0; ni < 4; ++ni) {
      const f32x4 bias4 = *(const f32x4*)&mlb[cur][ni * 16 + rg * 4];
#pragma unroll
      for (int mi = 0; mi < 2; ++mi) {
        const float p0 = exp2f(fmaf(s2[mi][ni][0], C1, bias4[0]));
        const float p1 = exp2f(fmaf(s2[mi][ni][1], C1, bias4[1]));
        const float p2 = exp2f(fmaf(s2[mi][ni][2], C1, bias4[2]));
        const float p3 = exp2f(fmaf(s2[mi][ni][3], C1, bias4[3]));
        l_part[mi] += (p0 + p1) + (p2 + p3);
        union { bfrag4 v; unsigned u[2]; } pk;
        pk.u[0] = cvt_pk_bf16(p0, p1);
        pk.u[1] = cvt_pk_bf16(p2, p3);
        pf[mi][ni] = pk.v;
      }
    }
#pragma unroll
    for (int ni = 0; ni < 4; ++ni) {
      bfrag4 vf[4];
#pragma unroll
      for (int di = 0; di < 4; ++di)
        vf[di] = *(const bfrag4*)&Vc[(di * 16 + col) * 72 + ni * 16 + rg * 4];
#pragma unroll
      for (int mi = 0; mi < 2; ++mi)
#pragma unroll
        for (int di = 0; di < 4; ++di)
          oa[mi][di] = mfma16k16(pf[mi][ni], vf[di], oa[mi][di]);
    }

    // ---- write next tile into the other buffer ----
    if (t < 7) {
      const int nb = cur ^ 1;
#pragma unroll
      for (int it = 0; it < 2; ++it) {
        const int idx = it * 256 + tid;
        const int key = idx >> 3, part = idx & 7;
        *(int4*)&Kl[nb][key * 72 + part * 8] = kreg[it];
      }
#pragma unroll
      for (int it = 0; it < 2; ++it) {
        const int idx = it * 256 + tid;
        const int d = idx >> 3, k8 = (idx & 7) * 8;
        *(int4*)&Vt[nb][d * 72 + k8] = vreg[it];
      }
      if (tid < 64) mlb[nb][tid] = mreg;
    }
    __syncthreads();   // one barrier per tile: readers done + next buf ready
  }

  // denominator: reduce across rg groups, bpermute 1/l to row layout
  float linv[2][4];
#pragma unroll
  for (int mi = 0; mi < 2; ++mi) {
    float l = l_part[mi];
    l += __shfl_xor(l, 16);
    l += __shfl_xor(l, 32);
#pragma unroll
    for (int r = 0; r < 4; ++r) {
      int lv = __builtin_amdgcn_ds_bpermute((rg * 4 + r) * 4, __float_as_int(l));
      linv[mi][r] = 1.f / __int_as_float(lv);
    }
  }
#pragma unroll
  for (int mi = 0; mi < 2; ++mi)
#pragma unroll
    for (int r = 0; r < 4; ++r) {
      const size_t row = (size_t)b * N_ + q0 + wq + mi * 16 + rg * 4 + r;
#pragma unroll
      for (int di = 0; di < 4; ++di)
        o[row * C_ + h * HD_ + di * 16 + col] = f2bf(oa[mi][di][r] * linv[mi][r]);
    }
}

// ---------------------------------------------------------------------------
// Launch
// ---------------------------------------------------------------------------
extern "C" void kernel_launch(void* const* d_in, const int* in_sizes, int n_in,
                              void* d_out, int out_size, void* d_ws, size_t ws_size,
                              hipStream_t stream) {
  (void)in_sizes; (void)n_in; (void)out_size; (void)ws_size;
  const float* x       = (const float*)d_in[0];
  const float* context = (const float*)d_in[1];
  const int*   mask    = (const int*)d_in[2];
  const float* ln_w    = (const float*)d_in[3];
  const float* ln_b    = (const float*)d_in[4];
  const float* Wq      = (const float*)d_in[5];
  const float* Wk      = (const float*)d_in[6];
  const float* Wv      = (const float*)d_in[7];
  const float* Wo      = (const float*)d_in[8];
  const float* Wctx    = (const float*)d_in[9];

  char* wsb = (char*)d_ws;
  ushort* qb    = (ushort*)(wsb + 0);          // 16384x512 bf16
  ushort* kb    = (ushort*)(wsb + 16777216);   //  8192x512
  ushort* vb    = (ushort*)(wsb + 25165824);   //  8192x512 (V^T: (b*512+e)*512+l)
  ushort* atto  = (ushort*)(wsb + 33554432);   // 16384x512 (attn out)
  ushort* ctx   = (ushort*)(wsb + 50331648);   //  8192x512 (projected context)
  ushort* wctxb = (ushort*)(wsb + 58720256);   //   512x768
  ushort* wqb   = (ushort*)(wsb + 59506688);   //   512x512 each
  ushort* wkb   = (ushort*)(wsb + 60030976);
  ushort* wvb   = (ushort*)(wsb + 60555264);
  ushort* wob   = (ushort*)(wsb + 61079552);
  ushort* hn    = (ushort*)(wsb + 61603840);   // 16384x512 bf16 (LN'd hidden)
  ushort* ctxb  = (ushort*)(wsb + 78381056);   //  8192x768 bf16 (context cast)
  // total 90,963,968 bytes

  cast6_kernel<<<7552, 256, 0, stream>>>(context, Wctx, Wq, Wk, Wv, Wo,
                                         ctxb, wctxb, wqb, wkb, wvb, wob);
  ln_kernel<<<dim3(B_, N_ / 64), 1024, 0, stream>>>(x, ln_w, ln_b, hn);
  // FUSED: ctx = ctxb @ Wctx^T || q = hn @ Wq^T (768 blk, XCD-friendly map)
  gemm_ctxq<<<768, 256, 0, stream>>>(ctxb, wctxb, ctx, hn, wqb, qb);
  // k row-major, v TRANSPOSED (e-major) for attn staging
  gemm_kv<<<dim3(64, 8), 256, 0, stream>>>(ctx, wkb, wvb, kb, vb);
  // XCD-swizzled 1D grid (T1): all q-blocks of one (b,h) on the same XCD
  attn_mfma<<<1024, 256, 0, stream>>>(qb, kb, vb, mask, atto);
  // out = transpose(atto @ Wo^T) + x, fused epilogue
  gemm_res<<<dim3(128, 4), 256, 0, stream>>>(atto, wob, x, (float*)d_out);
}